// Round 1
// baseline (560.138 us; speedup 1.0000x reference)
//
#include <hip/hip_runtime.h>
#include <math.h>

#define BATCH 16
#define KVH   8
#define QM    4
#define HD    128
#define SLEN  4096

// ---------------------------------------------------------------------------
// Stage 1: flash-decode partials, fixed-max (m=0) softmax, software-pipelined.
//   R3 change: kv-cooperative blocks. grid (nseg, BATCH), block 512 (8 waves).
//   Wave w = kv head w. All 8 waves of a block walk the SAME positions of the
//   SAME batch, so the block's combined fetch per iteration is a CONTIGUOUS
//   32KB K + 32KB V stream (8 positions x full 4KB (KVH*HD) rows) instead of
//   8 temporally-scattered 512B@4KB-stride streams. Targets DRAM row/channel
//   efficiency (measured: 1.74 TB/s HBM, vs 6.6 TB/s for the memset of the
//   same harness -- pattern, not capacity, is the limiter).
//   Inner loop unchanged from the 545us version:
//   Lane layout: g = lane>>4 (position group), c = lane&15.
//   Each group handles 2 adjacent positions per iteration (8/wave-iter).
//   Pipeline: K(+mask) for iter i+1 is register-prefetched during iter i;
//   V for iter i is loaded at the top of iter i and its latency hides under
//   the dot + 4-level swizzle reduce + exp of the (already-resident) K.
//   All register arrays fully unrolled / constant-indexed (runtime idx ->
//   scratch). Scores bounded (|s| <= ~11) so exp with fixed max 0 is safe in
//   fp32; stage-2 merge is a plain sum.
// ---------------------------------------------------------------------------
__global__ __launch_bounds__(512, 4) void attn_partial(
    const float* __restrict__ Q, const float* __restrict__ Kn,
    const float* __restrict__ Vn, const float* __restrict__ Kc,
    const float* __restrict__ Vc, const float* __restrict__ Mask,
    float* __restrict__ Op, float* __restrict__ Lp,
    int nseg, int seglen)
{
    const int tid  = threadIdx.x;
    const int kv   = tid >> 6;     // wave index = kv head (8 waves/block)
    const int lane = tid & 63;
    const int g    = lane >> 4;    // position group 0..3
    const int c    = lane & 15;    // 16 lanes per position
    const int seg  = blockIdx.x;
    const int b    = blockIdx.y;

    const float scale = 0.088388347648318447f;  // 1/sqrt(128)

    // Q fragments for the 4 GQA heads, pre-scaled. element d = j*64 + c*4.
    const float* qb = Q + (size_t)b * (KVH * QM * HD) + kv * (QM * HD) + c * 4;
    float4 q[QM][2];
#pragma unroll
    for (int h = 0; h < QM; ++h) {
#pragma unroll
        for (int j = 0; j < 2; ++j) {
            float4 t = *(const float4*)(qb + h * HD + j * 64);
            q[h][j].x = t.x * scale; q[h][j].y = t.y * scale;
            q[h][j].z = t.z * scale; q[h][j].w = t.w * scale;
        }
    }

    float  l[QM] = {0.f, 0.f, 0.f, 0.f};
    float4 o[QM][2];
#pragma unroll
    for (int h = 0; h < QM; ++h)
#pragma unroll
        for (int j = 0; j < 2; ++j) o[h][j] = make_float4(0.f, 0.f, 0.f, 0.f);

    const size_t rowstride = (size_t)KVH * HD;  // floats between cache positions
    const float* kc   = Kc + (size_t)b * SLEN * rowstride + kv * HD + c * 4;
    const float* vc   = Vc + (size_t)b * SLEN * rowstride + kv * HD + c * 4;
    const float* mrow = Mask + (size_t)b * SLEN;

    const int start = seg * seglen;
    const int niter = seglen >> 3;   // 8 positions per iteration (2 per group)

    // --- prefetch K + mask for the first position pair of this group ---
    int pA = start + g * 2;
    const float* kpA = kc + (size_t)pA * rowstride;
    const float* kpB = kpA + rowstride;
    float4 ka0 = *(const float4*)(kpA);
    float4 ka1 = *(const float4*)(kpA + 64);
    float4 kb0 = *(const float4*)(kpB);
    float4 kb1 = *(const float4*)(kpB + 64);
    float  ma  = mrow[pA];
    float  mb  = mrow[pA + 1];

    for (int i = 0; i < niter; ++i) {
        const int pos = start + i * 8 + g * 2;

        // V for the current pair: issued first, consumed last (latency hidden
        // under dot + swizzle reduce + exp on the prefetched K).
        const float* vpA = vc + (size_t)pos * rowstride;
        const float* vpB = vpA + rowstride;
        float4 va0 = *(const float4*)(vpA);
        float4 va1 = *(const float4*)(vpA + 64);
        float4 vb0 = *(const float4*)(vpB);
        float4 vb1 = *(const float4*)(vpB + 64);

        // K + mask prefetch for the next pair (clamped dummy on last iter).
        int pn = pos + 8;
        if (i + 1 == niter) pn = start + g * 2;
        const float* kpAn = kc + (size_t)pn * rowstride;
        const float* kpBn = kpAn + rowstride;
        float4 nka0 = *(const float4*)(kpAn);
        float4 nka1 = *(const float4*)(kpAn + 64);
        float4 nkb0 = *(const float4*)(kpBn);
        float4 nkb1 = *(const float4*)(kpBn + 64);
        float  nma  = mrow[pn];
        float  nmb  = mrow[pn + 1];

        // dots for both positions, 4 heads each (K already in registers)
        float sA[QM], sB[QM];
#pragma unroll
        for (int h = 0; h < QM; ++h) {
            sA[h] = q[h][0].x * ka0.x + q[h][0].y * ka0.y + q[h][0].z * ka0.z + q[h][0].w * ka0.w
                  + q[h][1].x * ka1.x + q[h][1].y * ka1.y + q[h][1].z * ka1.z + q[h][1].w * ka1.w;
            sB[h] = q[h][0].x * kb0.x + q[h][0].y * kb0.y + q[h][0].z * kb0.z + q[h][0].w * kb0.w
                  + q[h][1].x * kb1.x + q[h][1].y * kb1.y + q[h][1].z * kb1.z + q[h][1].w * kb1.w;
        }
        // reduce across the 16 lanes (4 dependent levels; 8 independent values
        // per level keep the DS pipe fed)
#pragma unroll
        for (int off = 1; off <= 8; off <<= 1) {
#pragma unroll
            for (int h = 0; h < QM; ++h) {
                sA[h] += __shfl_xor(sA[h], off);
                sB[h] += __shfl_xor(sB[h], off);
            }
        }

#pragma unroll
        for (int h = 0; h < QM; ++h) {
            float wA = __expf(sA[h] + ma);   // fixed max = 0
            float wB = __expf(sB[h] + mb);
            l[h] += wA + wB;
            o[h][0].x += wA * va0.x + wB * vb0.x;
            o[h][0].y += wA * va0.y + wB * vb0.y;
            o[h][0].z += wA * va0.z + wB * vb0.z;
            o[h][0].w += wA * va0.w + wB * vb0.w;
            o[h][1].x += wA * va1.x + wB * vb1.x;
            o[h][1].y += wA * va1.y + wB * vb1.y;
            o[h][1].z += wA * va1.z + wB * vb1.z;
            o[h][1].w += wA * va1.w + wB * vb1.w;
        }

        ka0 = nka0; ka1 = nka1; kb0 = nkb0; kb1 = nkb1;
        ma = nma; mb = nmb;
    }

    // tail: newly-appended token (position SLEN), mask pad = 0.
    // All groups compute it; only group 0's contribution is kept (gate).
    if (seg == nseg - 1) {
        const float* kp = Kn + (size_t)b * (KVH * HD) + kv * HD + c * 4;
        const float* vp = Vn + (size_t)b * (KVH * HD) + kv * HD + c * 4;
        float4 k0 = *(const float4*)(kp);
        float4 k1 = *(const float4*)(kp + 64);
        float4 v0 = *(const float4*)(vp);
        float4 v1 = *(const float4*)(vp + 64);
        float s[QM];
#pragma unroll
        for (int h = 0; h < QM; ++h)
            s[h] = q[h][0].x * k0.x + q[h][0].y * k0.y + q[h][0].z * k0.z + q[h][0].w * k0.w
                 + q[h][1].x * k1.x + q[h][1].y * k1.y + q[h][1].z * k1.z + q[h][1].w * k1.w;
#pragma unroll
        for (int off = 1; off <= 8; off <<= 1) {
#pragma unroll
            for (int h = 0; h < QM; ++h) s[h] += __shfl_xor(s[h], off);
        }
        const float gate = (g == 0) ? 1.f : 0.f;
#pragma unroll
        for (int h = 0; h < QM; ++h) {
            float w = __expf(s[h]) * gate;
            l[h] += w;
            o[h][0].x += w * v0.x; o[h][0].y += w * v0.y;
            o[h][0].z += w * v0.z; o[h][0].w += w * v0.w;
            o[h][1].x += w * v1.x; o[h][1].y += w * v1.y;
            o[h][1].z += w * v1.z; o[h][1].w += w * v1.w;
        }
    }

    // combine the 4 position groups: 2 symmetric xor levels, constant indices.
#pragma unroll
    for (int off = 16; off <= 32; off <<= 1) {
#pragma unroll
        for (int h = 0; h < QM; ++h) {
            l[h]      += __shfl_xor(l[h],      off);
            o[h][0].x += __shfl_xor(o[h][0].x, off);
            o[h][0].y += __shfl_xor(o[h][0].y, off);
            o[h][0].z += __shfl_xor(o[h][0].z, off);
            o[h][0].w += __shfl_xor(o[h][0].w, off);
            o[h][1].x += __shfl_xor(o[h][1].x, off);
            o[h][1].y += __shfl_xor(o[h][1].y, off);
            o[h][1].z += __shfl_xor(o[h][1].z, off);
            o[h][1].w += __shfl_xor(o[h][1].w, off);
        }
    }

    // write-out: group 0 writes all 4 heads (constant h indices).
    const size_t sidx = ((size_t)b * KVH + kv) * nseg + seg;
    if (g == 0) {
#pragma unroll
        for (int h = 0; h < QM; ++h) {
            float* op = Op + (sidx * QM + h) * HD + c * 4;
            *(float4*)(op)      = o[h][0];
            *(float4*)(op + 64) = o[h][1];
            if (c == 0) Lp[sidx * QM + h] = l[h];
        }
    }
}

// ---------------------------------------------------------------------------
// Stage 2: plain-sum merge (fixed max). grid BATCH*KVH*QM blocks x HD threads.
// ---------------------------------------------------------------------------
__global__ __launch_bounds__(HD) void attn_combine(
    const float* __restrict__ Op, const float* __restrict__ Lp,
    float* __restrict__ out, int nseg)
{
    const int d  = threadIdx.x;
    const int h  = blockIdx.x & (QM - 1);
    const int kv = (blockIdx.x >> 2) & (KVH - 1);
    const int b  = blockIdx.x >> 5;
    const size_t base = ((size_t)b * KVH + kv) * nseg;

    float acc = 0.f, L = 0.f;
    for (int cseg = 0; cseg < nseg; ++cseg) {
        acc += Op[(base + cseg) * QM * HD + h * HD + d];
        L   += Lp[(base + cseg) * QM + h];
    }
    out[((size_t)b * KVH * QM + kv * QM + h) * HD + d] = acc / L;
}

// ---------------------------------------------------------------------------
extern "C" void kernel_launch(void* const* d_in, const int* in_sizes, int n_in,
                              void* d_out, int out_size, void* d_ws, size_t ws_size,
                              hipStream_t stream)
{
    const float* Q    = (const float*)d_in[0];
    const float* K    = (const float*)d_in[1];
    const float* V    = (const float*)d_in[2];
    const float* Kc   = (const float*)d_in[3];
    const float* Vc   = (const float*)d_in[4];
    const float* Mask = (const float*)d_in[5];
    float* out = (float*)d_out;

    // nseg=64 -> 1024 blocks of 8 waves. auto-shrink if workspace too small.
    int nseg = 64;
    const size_t per_seg = (size_t)BATCH * KVH * QM * (HD + 1) * sizeof(float);
    while (nseg > 8 && (size_t)nseg * per_seg > ws_size) nseg >>= 1;
    const int seglen = SLEN / nseg;

    float* Op = (float*)d_ws;
    float* Lp = Op + (size_t)nseg * BATCH * KVH * QM * HD;

    dim3 grid1(nseg, BATCH);
    attn_partial<<<grid1, 512, 0, stream>>>(Q, K, V, Kc, Vc, Mask, Op, Lp, nseg, seglen);
    attn_combine<<<dim3(BATCH * KVH * QM), HD, 0, stream>>>(Op, Lp, out, nseg);
}

// Round 2
// 537.505 us; speedup vs baseline: 1.0421x; 1.0421x over previous
//
#include <hip/hip_runtime.h>
#include <math.h>

#define BATCH 16
#define KVH   8
#define QM    4
#define HD    128
#define SLEN  4096

// ---------------------------------------------------------------------------
// Stage 1: flash-decode partials, fixed-max (m=0) softmax, software-pipelined.
//   R4: kv-cooperative blocks WITHOUT spills.
//   grid (nseg, BATCH), block 512 (8 waves). Wave w = kv head w; all 8 waves
//   walk the same positions of the same batch -> block fetch per iteration is
//   a contiguous 32KB K + 32KB V stream.
//   R1 lesson: __launch_bounds__(512,4) made the allocator pick 64 VGPRs and
//   spill ~20 regs (WRITE_SIZE 17->70MB, scratch in the inner loop). The
//   kernel needs ~90 live VGPRs (q[4][2] + o[4][2] + K dbl-buffer + V).
//   (512,2) caps at 256 -> allocator takes what it needs, no spill; at ~90
//   VGPRs the HW tier is still 16 waves/CU (2 blocks/CU, ~50% occupancy).
//   Inner loop unchanged from the 545us version:
//   Lane layout: g = lane>>4 (position group), c = lane&15.
//   Each group handles 2 adjacent positions per iteration (8/wave-iter).
//   Pipeline: K(+mask) for iter i+1 register-prefetched during iter i; V for
//   iter i loaded at top of iter i, latency hidden under dot+reduce+exp.
//   All register arrays fully unrolled / constant-indexed.
//   Scores bounded (|s| <= ~11) so exp with fixed max 0 is safe in fp32;
//   stage-2 merge is a plain sum.
// ---------------------------------------------------------------------------
__global__ __launch_bounds__(512, 2) void attn_partial(
    const float* __restrict__ Q, const float* __restrict__ Kn,
    const float* __restrict__ Vn, const float* __restrict__ Kc,
    const float* __restrict__ Vc, const float* __restrict__ Mask,
    float* __restrict__ Op, float* __restrict__ Lp,
    int nseg, int seglen)
{
    const int tid  = threadIdx.x;
    const int kv   = tid >> 6;     // wave index = kv head (8 waves/block)
    const int lane = tid & 63;
    const int g    = lane >> 4;    // position group 0..3
    const int c    = lane & 15;    // 16 lanes per position
    const int seg  = blockIdx.x;
    const int b    = blockIdx.y;

    const float scale = 0.088388347648318447f;  // 1/sqrt(128)

    // Q fragments for the 4 GQA heads, pre-scaled. element d = j*64 + c*4.
    const float* qb = Q + (size_t)b * (KVH * QM * HD) + kv * (QM * HD) + c * 4;
    float4 q[QM][2];
#pragma unroll
    for (int h = 0; h < QM; ++h) {
#pragma unroll
        for (int j = 0; j < 2; ++j) {
            float4 t = *(const float4*)(qb + h * HD + j * 64);
            q[h][j].x = t.x * scale; q[h][j].y = t.y * scale;
            q[h][j].z = t.z * scale; q[h][j].w = t.w * scale;
        }
    }

    float  l[QM] = {0.f, 0.f, 0.f, 0.f};
    float4 o[QM][2];
#pragma unroll
    for (int h = 0; h < QM; ++h)
#pragma unroll
        for (int j = 0; j < 2; ++j) o[h][j] = make_float4(0.f, 0.f, 0.f, 0.f);

    const size_t rowstride = (size_t)KVH * HD;  // floats between cache positions
    const float* kc   = Kc + (size_t)b * SLEN * rowstride + kv * HD + c * 4;
    const float* vc   = Vc + (size_t)b * SLEN * rowstride + kv * HD + c * 4;
    const float* mrow = Mask + (size_t)b * SLEN;

    const int start = seg * seglen;
    const int niter = seglen >> 3;   // 8 positions per iteration (2 per group)

    // --- prefetch K + mask for the first position pair of this group ---
    int pA = start + g * 2;
    const float* kpA = kc + (size_t)pA * rowstride;
    const float* kpB = kpA + rowstride;
    float4 ka0 = *(const float4*)(kpA);
    float4 ka1 = *(const float4*)(kpA + 64);
    float4 kb0 = *(const float4*)(kpB);
    float4 kb1 = *(const float4*)(kpB + 64);
    float  ma  = mrow[pA];
    float  mb  = mrow[pA + 1];

    for (int i = 0; i < niter; ++i) {
        const int pos = start + i * 8 + g * 2;

        // V for the current pair: issued first, consumed last (latency hidden
        // under dot + swizzle reduce + exp on the prefetched K).
        const float* vpA = vc + (size_t)pos * rowstride;
        const float* vpB = vpA + rowstride;
        float4 va0 = *(const float4*)(vpA);
        float4 va1 = *(const float4*)(vpA + 64);
        float4 vb0 = *(const float4*)(vpB);
        float4 vb1 = *(const float4*)(vpB + 64);

        // K + mask prefetch for the next pair (clamped dummy on last iter).
        int pn = pos + 8;
        if (i + 1 == niter) pn = start + g * 2;
        const float* kpAn = kc + (size_t)pn * rowstride;
        const float* kpBn = kpAn + rowstride;
        float4 nka0 = *(const float4*)(kpAn);
        float4 nka1 = *(const float4*)(kpAn + 64);
        float4 nkb0 = *(const float4*)(kpBn);
        float4 nkb1 = *(const float4*)(kpBn + 64);
        float  nma  = mrow[pn];
        float  nmb  = mrow[pn + 1];

        // dots for both positions, 4 heads each (K already in registers)
        float sA[QM], sB[QM];
#pragma unroll
        for (int h = 0; h < QM; ++h) {
            sA[h] = q[h][0].x * ka0.x + q[h][0].y * ka0.y + q[h][0].z * ka0.z + q[h][0].w * ka0.w
                  + q[h][1].x * ka1.x + q[h][1].y * ka1.y + q[h][1].z * ka1.z + q[h][1].w * ka1.w;
            sB[h] = q[h][0].x * kb0.x + q[h][0].y * kb0.y + q[h][0].z * kb0.z + q[h][0].w * kb0.w
                  + q[h][1].x * kb1.x + q[h][1].y * kb1.y + q[h][1].z * kb1.z + q[h][1].w * kb1.w;
        }
        // reduce across the 16 lanes (4 dependent levels; 8 independent values
        // per level keep the DS pipe fed)
#pragma unroll
        for (int off = 1; off <= 8; off <<= 1) {
#pragma unroll
            for (int h = 0; h < QM; ++h) {
                sA[h] += __shfl_xor(sA[h], off);
                sB[h] += __shfl_xor(sB[h], off);
            }
        }

#pragma unroll
        for (int h = 0; h < QM; ++h) {
            float wA = __expf(sA[h] + ma);   // fixed max = 0
            float wB = __expf(sB[h] + mb);
            l[h] += wA + wB;
            o[h][0].x += wA * va0.x + wB * vb0.x;
            o[h][0].y += wA * va0.y + wB * vb0.y;
            o[h][0].z += wA * va0.z + wB * vb0.z;
            o[h][0].w += wA * va0.w + wB * vb0.w;
            o[h][1].x += wA * va1.x + wB * vb1.x;
            o[h][1].y += wA * va1.y + wB * vb1.y;
            o[h][1].z += wA * va1.z + wB * vb1.z;
            o[h][1].w += wA * va1.w + wB * vb1.w;
        }

        ka0 = nka0; ka1 = nka1; kb0 = nkb0; kb1 = nkb1;
        ma = nma; mb = nmb;
    }

    // tail: newly-appended token (position SLEN), mask pad = 0.
    // All groups compute it; only group 0's contribution is kept (gate).
    if (seg == nseg - 1) {
        const float* kp = Kn + (size_t)b * (KVH * HD) + kv * HD + c * 4;
        const float* vp = Vn + (size_t)b * (KVH * HD) + kv * HD + c * 4;
        float4 k0 = *(const float4*)(kp);
        float4 k1 = *(const float4*)(kp + 64);
        float4 v0 = *(const float4*)(vp);
        float4 v1 = *(const float4*)(vp + 64);
        float s[QM];
#pragma unroll
        for (int h = 0; h < QM; ++h)
            s[h] = q[h][0].x * k0.x + q[h][0].y * k0.y + q[h][0].z * k0.z + q[h][0].w * k0.w
                 + q[h][1].x * k1.x + q[h][1].y * k1.y + q[h][1].z * k1.z + q[h][1].w * k1.w;
#pragma unroll
        for (int off = 1; off <= 8; off <<= 1) {
#pragma unroll
            for (int h = 0; h < QM; ++h) s[h] += __shfl_xor(s[h], off);
        }
        const float gate = (g == 0) ? 1.f : 0.f;
#pragma unroll
        for (int h = 0; h < QM; ++h) {
            float w = __expf(s[h]) * gate;
            l[h] += w;
            o[h][0].x += w * v0.x; o[h][0].y += w * v0.y;
            o[h][0].z += w * v0.z; o[h][0].w += w * v0.w;
            o[h][1].x += w * v1.x; o[h][1].y += w * v1.y;
            o[h][1].z += w * v1.z; o[h][1].w += w * v1.w;
        }
    }

    // combine the 4 position groups: 2 symmetric xor levels, constant indices.
#pragma unroll
    for (int off = 16; off <= 32; off <<= 1) {
#pragma unroll
        for (int h = 0; h < QM; ++h) {
            l[h]      += __shfl_xor(l[h],      off);
            o[h][0].x += __shfl_xor(o[h][0].x, off);
            o[h][0].y += __shfl_xor(o[h][0].y, off);
            o[h][0].z += __shfl_xor(o[h][0].z, off);
            o[h][0].w += __shfl_xor(o[h][0].w, off);
            o[h][1].x += __shfl_xor(o[h][1].x, off);
            o[h][1].y += __shfl_xor(o[h][1].y, off);
            o[h][1].z += __shfl_xor(o[h][1].z, off);
            o[h][1].w += __shfl_xor(o[h][1].w, off);
        }
    }

    // write-out: group 0 writes all 4 heads (constant h indices).
    const size_t sidx = ((size_t)b * KVH + kv) * nseg + seg;
    if (g == 0) {
#pragma unroll
        for (int h = 0; h < QM; ++h) {
            float* op = Op + (sidx * QM + h) * HD + c * 4;
            *(float4*)(op)      = o[h][0];
            *(float4*)(op + 64) = o[h][1];
            if (c == 0) Lp[sidx * QM + h] = l[h];
        }
    }
}

// ---------------------------------------------------------------------------
// Stage 2: plain-sum merge (fixed max). grid BATCH*KVH*QM blocks x HD threads.
// ---------------------------------------------------------------------------
__global__ __launch_bounds__(HD) void attn_combine(
    const float* __restrict__ Op, const float* __restrict__ Lp,
    float* __restrict__ out, int nseg)
{
    const int d  = threadIdx.x;
    const int h  = blockIdx.x & (QM - 1);
    const int kv = (blockIdx.x >> 2) & (KVH - 1);
    const int b  = blockIdx.x >> 5;
    const size_t base = ((size_t)b * KVH + kv) * nseg;

    float acc = 0.f, L = 0.f;
    for (int cseg = 0; cseg < nseg; ++cseg) {
        acc += Op[(base + cseg) * QM * HD + h * HD + d];
        L   += Lp[(base + cseg) * QM + h];
    }
    out[((size_t)b * KVH * QM + kv * QM + h) * HD + d] = acc / L;
}

// ---------------------------------------------------------------------------
extern "C" void kernel_launch(void* const* d_in, const int* in_sizes, int n_in,
                              void* d_out, int out_size, void* d_ws, size_t ws_size,
                              hipStream_t stream)
{
    const float* Q    = (const float*)d_in[0];
    const float* K    = (const float*)d_in[1];
    const float* V    = (const float*)d_in[2];
    const float* Kc   = (const float*)d_in[3];
    const float* Vc   = (const float*)d_in[4];
    const float* Mask = (const float*)d_in[5];
    float* out = (float*)d_out;

    // nseg=64 -> 1024 blocks of 8 waves. auto-shrink if workspace too small.
    int nseg = 64;
    const size_t per_seg = (size_t)BATCH * KVH * QM * (HD + 1) * sizeof(float);
    while (nseg > 8 && (size_t)nseg * per_seg > ws_size) nseg >>= 1;
    const int seglen = SLEN / nseg;

    float* Op = (float*)d_ws;
    float* Lp = Op + (size_t)nseg * BATCH * KVH * QM * HD;

    dim3 grid1(nseg, BATCH);
    attn_partial<<<grid1, 512, 0, stream>>>(Q, K, V, Kc, Vc, Mask, Op, Lp, nseg, seglen);
    attn_combine<<<dim3(BATCH * KVH * QM), HD, 0, stream>>>(Op, Lp, out, nseg);
}